// Round 5
// baseline (327.462 us; speedup 1.0000x reference)
//
#include <hip/hip_runtime.h>

using u32 = unsigned int;
typedef int v4i __attribute__((ext_vector_type(4)));

// ---------------- workspace layout (bytes) ----------------
constexpr int  N_IMG   = 16;
constexpr int  PADROW  = 4096;          // 64 cols * 64 ch bytes
constexpr int  ROWS_PI = 58;            // 56 real + top/bottom pad rows
constexpr size_t OFS_QX  = 4096;
constexpr size_t SZ_QPAD = (size_t)(1 + N_IMG * ROWS_PI) * PADROW;   // 3,805,184
constexpr size_t OFS_Q1  = OFS_QX + SZ_QPAD;
constexpr size_t OFS_O1  = OFS_Q1 + SZ_QPAD;
constexpr size_t SZ_OF   = (size_t)N_IMG * 56 * 56 * 64 * 4;         // 12,845,056
constexpr size_t OFS_O2  = OFS_O1 + SZ_OF;
constexpr size_t OFS_QW1 = OFS_O2 + SZ_OF;
constexpr size_t OFS_QW2 = OFS_QW1 + 36864;
constexpr size_t OFS_WB1 = OFS_QW2 + 36864;
constexpr size_t OFS_WB2 = OFS_WB1 + 18432;
constexpr size_t OFS_WSUM= OFS_WB2 + 18432;
constexpr size_t OFS_STX = OFS_WSUM + 256;      // 4608 ints (aggregated over images)
constexpr size_t OFS_STQ = OFS_STX + 294912;
constexpr size_t WS_NEED = OFS_STQ + 294912;
constexpr size_t OUTN    = (size_t)16 * 64 * 56 * 56;                // 3,211,264

// ---------------- K0: zero scalars + aggregated stats + wsum ----------------
__global__ __launch_bounds__(256) void k_init(float* scal, int* gstx, int* gstq, int* wsum) {
    int i = blockIdx.x * 256 + threadIdx.x;
    if (i < 8) scal[i] = 0.f;
    if (i < 64) wsum[i] = 0;
    if (i < 4608) { gstx[i] = 0; gstq[i] = 0; }
}

// ---------------- K1: absmax of x / w1 / w2 ----------------
__global__ __launch_bounds__(256) void k_absmax(const float* __restrict__ x,
                                                const float* __restrict__ w1,
                                                const float* __restrict__ w2,
                                                float* __restrict__ scal) {
    const float* p; int n; int slot;
    if (blockIdx.y == 0)      { p = x;  n = 16*64*56*56; slot = 0; }
    else if (blockIdx.y == 1) { p = w1; n = 64*64*9;     slot = 1; }
    else                      { p = w2; n = 64*64*9;     slot = 2; }
    float m = 0.f;
    for (int i = blockIdx.x * 256 + threadIdx.x; i < n; i += gridDim.x * 256)
        m = fmaxf(m, fabsf(p[i]));
    __shared__ float red[256];
    red[threadIdx.x] = m; __syncthreads();
    for (int s = 128; s > 0; s >>= 1) {
        if (threadIdx.x < s) red[threadIdx.x] = fmaxf(red[threadIdx.x], red[threadIdx.x + s]);
        __syncthreads();
    }
    if (threadIdx.x == 0) atomicMax((u32*)(scal + slot), __float_as_uint(red[0]));
}

// ---------------- helpers for fused quant+stats ----------------
static __device__ __forceinline__ void unpack_acc(u32 v, u32 pk[8]) {
#pragma unroll
    for (int k = 0; k < 8; k++) pk[k] += (v >> k) & 0x01010101u;
}

// conflict-free tree reduction of packed byte counters over the xo dimension.
// red layout: red[k*256 + t], t = xo*16 + ci4. Byte counters must be <=16 per thread
// (8-thread partial sums stay <=128 < 256). 512 conditional global atomics at the end.
static __device__ __forceinline__ void reduce_tree(u32* red, int* gdst, const u32 pk[8], int t) {
#pragma unroll
    for (int k = 0; k < 8; k++) red[k * 256 + t] = pk[k];
    __syncthreads();
    if (t < 128) {
#pragma unroll
        for (int k = 0; k < 8; k++) red[k * 256 + t] += red[k * 256 + t + 128];
    }
    __syncthreads();
    if (t < 64) {
#pragma unroll
        for (int k = 0; k < 8; k++) red[k * 256 + t] += red[k * 256 + t + 64];
    }
    __syncthreads();
    if (t < 32) {
#pragma unroll
        for (int k = 0; k < 8; k++) red[k * 256 + t] += red[k * 256 + t + 32];
    }
    __syncthreads();
#pragma unroll
    for (int p = t; p < 512; p += 256) {
        int ci = p >> 3, k = p & 7, ci4 = ci >> 2, b = ci & 3;
        u32 e = red[k * 256 + ci4], o = red[k * 256 + 16 + ci4];
        int sum = (int)((e >> (8 * b)) & 0xFF) + (int)((o >> (8 * b)) & 0xFF);
        if (sum) atomicAdd(&gdst[p], sum);
    }
    __syncthreads();
}

static __device__ __forceinline__ void direct_atomics(int* gdst, const u32 pk[8], int ci4) {
#pragma unroll
    for (int k = 0; k < 8; k++)
#pragma unroll
        for (int b = 0; b < 4; b++) {
            int val = (pk[k] >> (8 * b)) & 0xFF;
            if (val) atomicAdd(&gdst[(ci4 * 4 + b) * 8 + k], val);
        }
}

// ---------------- K2/K6 fused: quantize 4 rows -> padded int8 + bit-stats ----------------
// WHICH=0: x (NCHW fp32) -> qx, pad 0x00, xorm 0.  WHICH=1: o1 (NHWC) -> q1-128, pad 0x80, xorm 0x80.
// gst layout: j*512 + ci*8 + k ; j: 0=T 1=Rtop 2=Rbot 3=Cleft 4=Cright 5=(0,0) 6=(0,55) 7=(55,0) 8=(55,55)
template <int WHICH>
__global__ __launch_bounds__(256) void k_quant_stats(const float* __restrict__ src,
                                                     char* __restrict__ qpad,
                                                     const float* __restrict__ scal,
                                                     int* __restrict__ gst) {
    int n = blockIdx.x, slab = blockIdx.y, t = threadIdx.x;
    __shared__ char lq[14336];           // 4 rows x 3584 B
    __shared__ u32 red[2048];
    float s = WHICH ? scal[3] / 255.f : scal[0] / 127.f;
    int y0 = slab * 4;

    // quantize 4 rows into LDS
#pragma unroll
    for (int r = 0; r < 4; r++) {
        if (WHICH == 0) {
            for (int j = t; j < 3584; j += 256) {
                int c = j / 56, xx = j - c * 56;
                float v = src[(size_t)n * 200704 + (size_t)c * 3136 + (y0 + r) * 56 + xx];
                float q = rintf(v / s);
                q = fminf(fmaxf(q, -127.f), 127.f);
                lq[r * 3584 + xx * 64 + c] = (char)(int)q;
            }
        } else {
            const float* orow = src + (size_t)(n * 56 + y0 + r) * 3584;
            for (int j = t; j < 3584; j += 256) {
                float vv = fmaxf(orow[j], 0.f);
                float q = fminf(rintf(vv / s), 255.f);
                lq[r * 3584 + j] = (char)((int)q - 128);
            }
        }
    }
    __syncthreads();

    const u32 PAD = WHICH ? 0x80808080u : 0u;
    u32* lqd = (u32*)lq;
    // write the 4 padded global rows (896 data dwords + 128 pad dwords each)
    for (int idx = t; idx < 4096; idx += 256) {
        int r = idx >> 10, jd = idx & 1023;
        u32 val = (jd < 896) ? lqd[r * 896 + jd] : PAD;
        ((u32*)(qpad + (size_t)(1 + n * ROWS_PI + y0 + r + 1) * PADROW))[jd] = val;
    }
    if (slab == 0) {
        u32* row = (u32*)(qpad + (size_t)(1 + n * ROWS_PI) * PADROW);
        for (int j = t; j < 1024; j += 256) row[j] = PAD;
        if (n == 0) {
            u32* r0 = (u32*)qpad;
            for (int j = t; j < 1024; j += 256) r0[j] = PAD;
        }
    }
    if (slab == 13) {
        u32* row = (u32*)(qpad + (size_t)(1 + n * ROWS_PI + 57) * PADROW);
        for (int j = t; j < 1024; j += 256) row[j] = PAD;
    }

    // ---- stats from LDS ----
    u32 xm = WHICH ? 0x80808080u : 0u;
    int ci4 = t & 15, xo = t >> 4;
    {   // main total (j=0)
        u32 pk[8] = {0,0,0,0,0,0,0,0};
#pragma unroll
        for (int r = 0; r < 4; r++)
#pragma unroll
            for (int jj = 0; jj < 4; jj++) {
                int xx = xo + 16 * jj;
                if (xx < 56) unpack_acc(lqd[r * 896 + xx * 16 + ci4] ^ xm, pk);
            }
        reduce_tree(red, gst + 0 * 512, pk, t);
    }
    // border cols: direct atomics from the 16 holding threads (counts <=4)
    if (xo == 0) {
        u32 pk[8] = {0,0,0,0,0,0,0,0};
#pragma unroll
        for (int r = 0; r < 4; r++) unpack_acc(lqd[r * 896 + ci4] ^ xm, pk);
        direct_atomics(gst + 3 * 512, pk, ci4);
    }
    if (xo == 7) {
        u32 pk[8] = {0,0,0,0,0,0,0,0};
#pragma unroll
        for (int r = 0; r < 4; r++) unpack_acc(lqd[r * 896 + 55 * 16 + ci4] ^ xm, pk);
        direct_atomics(gst + 4 * 512, pk, ci4);
    }
    if (slab == 0) {   // Rtop (row r=0) + corners 5,6
        u32 pk[8] = {0,0,0,0,0,0,0,0};
#pragma unroll
        for (int jj = 0; jj < 4; jj++) {
            int xx = xo + 16 * jj;
            if (xx < 56) unpack_acc(lqd[xx * 16 + ci4] ^ xm, pk);
        }
        reduce_tree(red, gst + 1 * 512, pk, t);
        if (t < 32) {
            int which = t >> 4, c4 = t & 15;
            u32 v = lqd[(which ? 55 : 0) * 16 + c4] ^ xm;
            u32 pc[8] = {0,0,0,0,0,0,0,0};
            unpack_acc(v, pc);
            direct_atomics(gst + (5 + which) * 512, pc, c4);
        }
    }
    if (slab == 13) {  // Rbot (row r=3) + corners 7,8
        u32 pk[8] = {0,0,0,0,0,0,0,0};
#pragma unroll
        for (int jj = 0; jj < 4; jj++) {
            int xx = xo + 16 * jj;
            if (xx < 56) unpack_acc(lqd[3 * 896 + xx * 16 + ci4] ^ xm, pk);
        }
        reduce_tree(red, gst + 2 * 512, pk, t);
        if (t < 32) {
            int which = t >> 4, c4 = t & 15;
            u32 v = lqd[3 * 896 + (which ? 55 : 0) * 16 + c4] ^ xm;
            u32 pc[8] = {0,0,0,0,0,0,0,0};
            unpack_acc(v, pc);
            direct_atomics(gst + (7 + which) * 512, pc, c4);
        }
    }
}

// ---------------- K2b: quantize weights -> [tap][co][ci], WB bit-stats, wsum ----------------
__global__ __launch_bounds__(256) void k_quant_w(const float* __restrict__ w1,
                                                 const float* __restrict__ w2,
                                                 char* __restrict__ qw1, char* __restrict__ qw2,
                                                 int* __restrict__ wb1, int* __restrict__ wb2,
                                                 int* __restrict__ wsum,
                                                 const float* __restrict__ scal) {
    int wsel = blockIdx.x, kp = blockIdx.y;
    const float* w = wsel ? w2 : w1;
    char* qw = wsel ? qw2 : qw1;
    int* wb  = wsel ? wb2 : wb1;
    float s = scal[1 + wsel] / 127.f;
    int t = threadIdx.x, co = t & 63, cg = t >> 6;
    int ci0 = cg * 16;
    signed char qv[16];
    int qsum = 0;
#pragma unroll
    for (int i = 0; i < 16; i++) {
        int ci = ci0 + i;
        float v = w[((size_t)co * 64 + ci) * 9 + kp];
        float qf = rintf(v / s);
        qf = fminf(fmaxf(qf, -127.f), 127.f);
        int q = (int)qf;
        qv[i] = (signed char)q;
        qsum += q;
    }
    u32 pk[4];
#pragma unroll
    for (int d = 0; d < 4; d++)
        pk[d] = ((u32)(unsigned char)qv[d*4]) | ((u32)(unsigned char)qv[d*4+1] << 8)
              | ((u32)(unsigned char)qv[d*4+2] << 16) | ((u32)(unsigned char)qv[d*4+3] << 24);
    *(uint4*)&qw[(size_t)(kp * 64 + co) * 64 + ci0] = *(uint4*)pk;
#pragma unroll
    for (int i = 0; i < 16; i++) {
        u32 u = (u32)(unsigned char)qv[i];
#pragma unroll
        for (int k = 0; k < 8; k++) {
            unsigned long long bal = __ballot((u >> k) & 1);
            if (co == 0) wb[((ci0 + i) * 8 + k) * 9 + kp] = __popcll(bal);
        }
    }
    if (wsel == 1) {
        __shared__ int wsl[256];
        wsl[t] = qsum; __syncthreads();
        if (t < 64) {
            int sum = wsl[t] + wsl[t + 64] + wsl[t + 128] + wsl[t + 192];
            atomicAdd(&wsum[t], sum);
        }
    }
}

// ---------------- K5/K7: int8 conv 3x3 via MFMA implicit GEMM ----------------
template <int SECOND>
__global__ __launch_bounds__(256, 2) void k_conv(const char* __restrict__ qin,
                                              const char* __restrict__ qw,
                                              const int* __restrict__ wsum,
                                              const char* __restrict__ qid,
                                              const float* __restrict__ g, const float* __restrict__ b,
                                              const float* __restrict__ m_, const float* __restrict__ v,
                                              const float* __restrict__ scal,
                                              float* __restrict__ outp, float* __restrict__ rmax) {
    __shared__ __align__(16) u32 lb[11520];    // B: 576 rows (tap,co) x 20 dw (64B data + 16B pad)
    __shared__ __align__(16) u32 lin[3960];    // input: 3 rows x 66 px x 20 dw
    __shared__ float red[256];
    int n = blockIdx.x, y = blockIdx.y, t = threadIdx.x;
    int w = t >> 6, lane = t & 63, mm = lane & 15, quad = lane >> 4;

    const uint4* bq4 = (const uint4*)qw;                 // 2304 uint4
    for (int j4 = t; j4 < 2304; j4 += 256) {
        int row = j4 >> 2, rem = j4 & 3;
        *(uint4*)&lb[row * 20 + rem * 4] = bq4[j4];
    }
    const uint4* qin4 = (const uint4*)qin;
    for (int g4 = t; g4 < 792; g4 += 256) {              // 3 rows x 264 uint4 (px -1..64)
        int ky = g4 / 264, r = g4 - ky * 264;
        int px = r >> 2, rem = r & 3;
        *(uint4*)&lin[(ky * 66 + px) * 20 + rem * 4] =
            qin4[(size_t)(1 + n * ROWS_PI + y + ky) * 256 - 4 + r];
    }
    __syncthreads();

    v4i acc[4] = {{0,0,0,0},{0,0,0,0},{0,0,0,0},{0,0,0,0}};
#pragma unroll
    for (int ky = 0; ky < 3; ky++) {
#pragma unroll
        for (int kx = 0; kx < 3; kx++) {
            int px = w * 16 + mm + kx;                   // lin idx = (x+kx-1)+1
            v4i a = *(const v4i*)&lin[(ky * 66 + px) * 20 + quad * 4];
            int tap = ky * 3 + kx;
#pragma unroll
            for (int nt = 0; nt < 4; nt++) {
                int co = nt * 16 + mm;
                v4i bf = *(const v4i*)&lb[(tap * 64 + co) * 20 + quad * 4];
                acc[nt] = __builtin_amdgcn_mfma_i32_16x16x64_i8(a, bf, acc[nt], 0, 0, 0);
            }
        }
    }
    // epilogue
    float sIn = SECOND ? scal[3] / 255.f : scal[0] / 127.f;
    float sW  = SECOND ? scal[2] / 127.f : scal[1] / 127.f;
    float sx = scal[0] / 127.f;
    float lmax = 0.f;
    size_t rowb = (size_t)(n * 56 + y) * 3584;
    const signed char* idrow = SECOND ? (const signed char*)(qid + (size_t)(2 + n * ROWS_PI + y) * PADROW)
                                      : (const signed char*)nullptr;
#pragma unroll
    for (int nt = 0; nt < 4; nt++) {
        int co = nt * 16 + mm;
        float inv = g[co] * rsqrtf(v[co] + 1e-5f);
        float alpha = sIn * sW * inv;
        float beta = b[co] - m_[co] * inv;
        int wofs = SECOND ? (wsum[co] << 7) : 0;
#pragma unroll
        for (int r = 0; r < 4; r++) {
            int x = w * 16 + quad * 4 + r;
            if (x < 56) {
                float o = (float)(acc[nt][r] + wofs) * alpha + beta;
                if (SECOND) o += sx * (float)idrow[x * 64 + co];
                outp[rowb + x * 64 + co] = o;
                lmax = fmaxf(lmax, o);
            }
        }
    }
    red[t] = lmax; __syncthreads();
    for (int s = 128; s > 0; s >>= 1) {
        if (t < s) red[t] = fmaxf(red[t], red[t + s]);
        __syncthreads();
    }
    if (t == 0) atomicMax((u32*)rmax, __float_as_uint(red[0]));
}

// ---------------- K8: final quantize + NHWC->NCHW transpose ----------------
__global__ __launch_bounds__(256) void k_final(const float* __restrict__ of,
                                               const float* __restrict__ scal,
                                               float* __restrict__ outp) {
    int n = blockIdx.x, y = blockIdx.y, t = threadIdx.x;
    __shared__ float lt[64 * 57];
    float s2 = scal[4] / 255.f;
    const float* orow = of + (size_t)(n * 56 + y) * 3584;
    for (int idx = t; idx < 3584; idx += 256) {
        int co = idx & 63, xx = idx >> 6;
        float vv = fmaxf(orow[idx], 0.f);
        float q = fminf(rintf(vv / s2), 255.f);
        lt[co * 57 + xx] = q * s2;
    }
    __syncthreads();
    for (int idx = t; idx < 3584; idx += 256) {
        int co = idx / 56, xx = idx - co * 56;
        outp[(size_t)n * 200704 + (size_t)co * 3136 + y * 56 + xx] = lt[co * 57 + xx];
    }
}

// ---------------- K9: combine bit-stats into HM_act / HM_energy ----------------
__global__ __launch_bounds__(512) void k_hm(const int* __restrict__ stx, const int* __restrict__ stq,
                                            const int* __restrict__ wb1, const int* __restrict__ wb2,
                                            float* __restrict__ outp) {
    int t = threadIdx.x;   // t = ci*8 + k
    long long act = 0, en = 0;
#pragma unroll
    for (int w = 0; w < 2; w++) {
        const int* st = w ? stq : stx;
        const int* wb = w ? wb2 : wb1;
        long long s[9];
#pragma unroll
        for (int j = 0; j < 9; j++) s[j] = st[j * 512 + t];
        const int* wrow = wb + t * 9;
        int w0 = wrow[0], w1_ = wrow[1], w2_ = wrow[2], w3 = wrow[3], w4 = wrow[4],
            w5 = wrow[5], w6 = wrow[6], w7 = wrow[7], w8 = wrow[8];
        long long wall = (long long)w0 + w1_ + w2_ + w3 + w4 + w5 + w6 + w7 + w8;
        long long wr0 = (long long)w0 + w1_ + w2_;
        long long wr2 = (long long)w6 + w7 + w8;
        long long wc0 = (long long)w0 + w3 + w6;
        long long wc2 = (long long)w2_ + w5 + w8;
        en += s[0] * wall - s[1] * wr2 - s[2] * wr0 - s[3] * wc2 - s[4] * wc0
            + s[5] * w8 + s[6] * w6 + s[7] * w2_ + s[8] * w0;
        act += s[0];
    }
    __shared__ long long r1[512];
    r1[t] = en; __syncthreads();
    for (int s = 256; s > 0; s >>= 1) { if (t < s) r1[t] += r1[t + s]; __syncthreads(); }
    long long etot = r1[0]; __syncthreads();
    r1[t] = act; __syncthreads();
    for (int s = 256; s > 0; s >>= 1) { if (t < s) r1[t] += r1[t + s]; __syncthreads(); }
    if (t == 0) {
        outp[OUTN]     = (float)r1[0];   // HM_act
        outp[OUTN + 1] = (float)etot;    // HM_energy
    }
}

extern "C" void kernel_launch(void* const* d_in, const int* in_sizes, int n_in,
                              void* d_out, int out_size, void* d_ws, size_t ws_size,
                              hipStream_t stream) {
    if (ws_size < WS_NEED) return;
    const float* x  = (const float*)d_in[0];
    const float* w1 = (const float*)d_in[1];
    const float* w2 = (const float*)d_in[2];
    const float* g1 = (const float*)d_in[3];
    const float* b1 = (const float*)d_in[4];
    const float* m1 = (const float*)d_in[5];
    const float* v1 = (const float*)d_in[6];
    const float* g2 = (const float*)d_in[7];
    const float* b2 = (const float*)d_in[8];
    const float* m2 = (const float*)d_in[9];
    const float* v2 = (const float*)d_in[10];
    char* ws = (char*)d_ws;
    float* scal = (float*)ws;
    char* qx = ws + OFS_QX;
    char* q1 = ws + OFS_Q1;
    float* o1 = (float*)(ws + OFS_O1);
    float* o2 = (float*)(ws + OFS_O2);
    char* qw1 = ws + OFS_QW1;
    char* qw2 = ws + OFS_QW2;
    int* wb1 = (int*)(ws + OFS_WB1);
    int* wb2 = (int*)(ws + OFS_WB2);
    int* wsum = (int*)(ws + OFS_WSUM);
    int* stx = (int*)(ws + OFS_STX);
    int* stq = (int*)(ws + OFS_STQ);
    float* outp = (float*)d_out;

    k_init<<<18, 256, 0, stream>>>(scal, stx, stq, wsum);
    k_absmax<<<dim3(1024, 3), 256, 0, stream>>>(x, w1, w2, scal);
    k_quant_stats<0><<<dim3(16, 14), 256, 0, stream>>>(x, qx, scal, stx);
    k_quant_w<<<dim3(2, 9), 256, 0, stream>>>(w1, w2, qw1, qw2, wb1, wb2, wsum, scal);
    k_conv<0><<<dim3(16, 56), 256, 0, stream>>>(qx, qw1, nullptr, nullptr,
                                                g1, b1, m1, v1, scal, o1, scal + 3);
    k_quant_stats<1><<<dim3(16, 14), 256, 0, stream>>>(o1, q1, scal, stq);
    k_conv<1><<<dim3(16, 56), 256, 0, stream>>>(q1, qw2, wsum, qx,
                                                g2, b2, m2, v2, scal, o2, scal + 4);
    k_final<<<dim3(16, 56), 256, 0, stream>>>(o2, scal, outp);
    k_hm<<<1, 512, 0, stream>>>(stx, stq, wb1, wb2, outp);
}

// Round 6
// 276.352 us; speedup vs baseline: 1.1849x; 1.1849x over previous
//
#include <hip/hip_runtime.h>

using u32 = unsigned int;
typedef int v4i __attribute__((ext_vector_type(4)));

// ---------------- workspace layout (bytes) ----------------
constexpr int  N_IMG   = 16;
constexpr int  PADROW  = 4096;          // 64 cols * 64 ch bytes
constexpr int  ROWS_PI = 58;            // 56 real + top/bottom pad rows
constexpr size_t OFS_QX  = 4096;
constexpr size_t SZ_QPAD = (size_t)(1 + N_IMG * ROWS_PI) * PADROW;   // 3,805,184
constexpr size_t OFS_Q1  = OFS_QX + SZ_QPAD;
constexpr size_t OFS_O1  = OFS_Q1 + SZ_QPAD;
constexpr size_t SZ_OF   = (size_t)N_IMG * 56 * 56 * 64 * 4;         // 12,845,056
constexpr size_t OFS_O2  = OFS_O1 + SZ_OF;                           // also: stage overlay
constexpr size_t OFS_QW1 = OFS_O2 + SZ_OF;
constexpr size_t OFS_QW2 = OFS_QW1 + 36864;
constexpr size_t OFS_WB1 = OFS_QW2 + 36864;
constexpr size_t OFS_WB2 = OFS_WB1 + 18432;
constexpr size_t OFS_WSUM= OFS_WB2 + 18432;
constexpr size_t OFS_STX = OFS_WSUM + 256;      // 4608 ints
constexpr size_t OFS_STQ = OFS_STX + 294912;
constexpr size_t WS_NEED = OFS_STQ + 294912;
constexpr size_t OUTN    = (size_t)16 * 64 * 56 * 56;                // 3,211,264

// stage layout (ints), overlaid on o2 region (dead during stats):
// j0/j3/j4: 224 blocks x 512 ; j1/j2/j5/j6/j7/j8: 16 blocks x 512
constexpr int STG_J0 = 0;
constexpr int STG_J3 = 224 * 512;
constexpr int STG_J4 = 2 * 224 * 512;
constexpr int STG_SM = 3 * 224 * 512;   // + idx*8192, idx: j1=0,j2=1,j5=2,j6=3,j7=4,j8=5

// ---------------- K0: zero scalars + wsum ----------------
__global__ __launch_bounds__(256) void k_init(float* scal, int* wsum) {
    int i = threadIdx.x;
    if (i < 8) scal[i] = 0.f;
    if (i < 64) wsum[i] = 0;
}

// ---------------- K1: absmax of x / w1 / w2 ----------------
__global__ __launch_bounds__(256) void k_absmax(const float* __restrict__ x,
                                                const float* __restrict__ w1,
                                                const float* __restrict__ w2,
                                                float* __restrict__ scal) {
    const float* p; int n; int slot;
    if (blockIdx.y == 0)      { p = x;  n = 16*64*56*56; slot = 0; }
    else if (blockIdx.y == 1) { p = w1; n = 64*64*9;     slot = 1; }
    else                      { p = w2; n = 64*64*9;     slot = 2; }
    float m = 0.f;
    for (int i = blockIdx.x * 256 + threadIdx.x; i < n; i += gridDim.x * 256)
        m = fmaxf(m, fabsf(p[i]));
    __shared__ float red[256];
    red[threadIdx.x] = m; __syncthreads();
    for (int s = 128; s > 0; s >>= 1) {
        if (threadIdx.x < s) red[threadIdx.x] = fmaxf(red[threadIdx.x], red[threadIdx.x + s]);
        __syncthreads();
    }
    if (threadIdx.x == 0) atomicMax((u32*)(scal + slot), __float_as_uint(red[0]));
}

// ---------------- K2: quantize x -> padded NHWC int8 ----------------
__global__ __launch_bounds__(256) void k_quant_x(const float* __restrict__ x,
                                                 char* __restrict__ qpad,
                                                 const float* __restrict__ scal) {
    int n = blockIdx.x, yy = blockIdx.y, t = threadIdx.x;
    u32* row = (u32*)(qpad + (size_t)(1 + n * ROWS_PI + yy) * PADROW);
    if (n == 0 && yy == 0) {                  // global leading zero row
        u32* r0 = (u32*)qpad;
        for (int j = t; j < 1024; j += 256) r0[j] = 0u;
    }
    if (yy == 0 || yy == 57) {                // per-image pad rows
        for (int j = t; j < 1024; j += 256) row[j] = 0u;
        return;
    }
    int y = yy - 1;
    float sx = scal[0] / 127.f;
    __shared__ char lq[4096];
    for (int idx = t; idx < 3584; idx += 256) {
        int c = idx / 56, xx = idx - c * 56;
        float v = x[(size_t)n * 200704 + (size_t)c * 3136 + y * 56 + xx];
        float q = rintf(v / sx);
        q = fminf(fmaxf(q, -127.f), 127.f);
        lq[xx * 64 + c] = (char)(int)q;
    }
    __syncthreads();
    u32* lqd = (u32*)lq;
    for (int j = t; j < 1024; j += 256) row[j] = (j < 896) ? lqd[j] : 0u;
}

// ---------------- K2b: quantize weights -> [tap][co][ci], WB bit-stats, wsum ----------------
__global__ __launch_bounds__(256) void k_quant_w(const float* __restrict__ w1,
                                                 const float* __restrict__ w2,
                                                 char* __restrict__ qw1, char* __restrict__ qw2,
                                                 int* __restrict__ wb1, int* __restrict__ wb2,
                                                 int* __restrict__ wsum,
                                                 const float* __restrict__ scal) {
    int wsel = blockIdx.x, kp = blockIdx.y;
    const float* w = wsel ? w2 : w1;
    char* qw = wsel ? qw2 : qw1;
    int* wb  = wsel ? wb2 : wb1;
    float s = scal[1 + wsel] / 127.f;
    int t = threadIdx.x, co = t & 63, cg = t >> 6;
    int ci0 = cg * 16;
    signed char qv[16];
    int qsum = 0;
#pragma unroll
    for (int i = 0; i < 16; i++) {
        int ci = ci0 + i;
        float v = w[((size_t)co * 64 + ci) * 9 + kp];
        float qf = rintf(v / s);
        qf = fminf(fmaxf(qf, -127.f), 127.f);
        int q = (int)qf;
        qv[i] = (signed char)q;
        qsum += q;
    }
    u32 pk[4];
#pragma unroll
    for (int d = 0; d < 4; d++)
        pk[d] = ((u32)(unsigned char)qv[d*4]) | ((u32)(unsigned char)qv[d*4+1] << 8)
              | ((u32)(unsigned char)qv[d*4+2] << 16) | ((u32)(unsigned char)qv[d*4+3] << 24);
    *(uint4*)&qw[(size_t)(kp * 64 + co) * 64 + ci0] = *(uint4*)pk;
#pragma unroll
    for (int i = 0; i < 16; i++) {
        u32 u = (u32)(unsigned char)qv[i];
#pragma unroll
        for (int k = 0; k < 8; k++) {
            unsigned long long bal = __ballot((u >> k) & 1);
            if (co == 0) wb[((ci0 + i) * 8 + k) * 9 + kp] = __popcll(bal);
        }
    }
    if (wsel == 1) {
        __shared__ int wsl[256];
        wsl[t] = qsum; __syncthreads();
        if (t < 64) {
            int sum = wsl[t] + wsl[t + 64] + wsl[t + 128] + wsl[t + 192];
            atomicAdd(&wsum[t], sum);
        }
    }
}

// ---------------- K3: bit stats -> per-block staging (NO contended atomics) ----------------
static __device__ __forceinline__ void unpack_acc(u32 v, u32 pk[8]) {
#pragma unroll
    for (int k = 0; k < 8; k++) pk[k] += (v >> k) & 0x01010101u;
}

// conflict-free packed-byte tree reduce over xo, then plain stores to stage slot
static __device__ __forceinline__ void tree_stage(u32* red, int* dst, const u32 pk[8], int t) {
#pragma unroll
    for (int k = 0; k < 8; k++) red[k * 256 + t] = pk[k];
    __syncthreads();
    if (t < 128) {
#pragma unroll
        for (int k = 0; k < 8; k++) red[k * 256 + t] += red[k * 256 + t + 128];
    }
    __syncthreads();
    if (t < 64) {
#pragma unroll
        for (int k = 0; k < 8; k++) red[k * 256 + t] += red[k * 256 + t + 64];
    }
    __syncthreads();
    if (t < 32) {
#pragma unroll
        for (int k = 0; k < 8; k++) red[k * 256 + t] += red[k * 256 + t + 32];
    }
    __syncthreads();
#pragma unroll
    for (int p = t; p < 512; p += 256) {
        int ci = p >> 3, k = p & 7, ci4 = ci >> 2, b = ci & 3;
        u32 e = red[k * 256 + ci4], o = red[k * 256 + 16 + ci4];
        dst[p] = (int)((e >> (8 * b)) & 0xFF) + (int)((o >> (8 * b)) & 0xFF);
    }
    __syncthreads();
}

// 16 threads (c4=0..15) each own 32 of the 512 entries: plain stores, full coverage
static __device__ __forceinline__ void stage_direct(int* dst, const u32 pk[8], int c4) {
#pragma unroll
    for (int k = 0; k < 8; k++)
#pragma unroll
        for (int b = 0; b < 4; b++)
            dst[(c4 * 4 + b) * 8 + k] = (int)((pk[k] >> (8 * b)) & 0xFF);
}

__global__ __launch_bounds__(256) void k_stats(const char* __restrict__ qpad, u32 xorm,
                                               int* __restrict__ stage) {
    int n = blockIdx.x, slab = blockIdx.y, t = threadIdx.x;
    int ci4 = t & 15, xo = t >> 4;
    const u32* img = (const u32*)(qpad + (size_t)(2 + n * ROWS_PI) * PADROW); // real row 0
    u32 xm = xorm * 0x01010101u;
    __shared__ u32 red[2048];
    int y0 = slab * 4, bi = n * 14 + slab;

    {   // j=0: main total over 4 rows
        u32 pk[8] = {0,0,0,0,0,0,0,0};
#pragma unroll
        for (int r = 0; r < 4; r++) {
            const u32* row = img + (size_t)(y0 + r) * 1024;
#pragma unroll
            for (int jj = 0; jj < 4; jj++) {
                int xx = xo + 16 * jj;
                if (xx < 56) unpack_acc(row[xx * 16 + ci4] ^ xm, pk);
            }
        }
        tree_stage(red, stage + STG_J0 + bi * 512, pk, t);
    }
    if (xo == 0) {   // j3: Cleft (x==0), 16 threads, direct stage
        u32 pk[8] = {0,0,0,0,0,0,0,0};
#pragma unroll
        for (int r = 0; r < 4; r++)
            unpack_acc(img[(size_t)(y0 + r) * 1024 + ci4] ^ xm, pk);
        stage_direct(stage + STG_J3 + bi * 512, pk, ci4);
    }
    if (xo == 7) {   // j4: Cright (x==55)
        u32 pk[8] = {0,0,0,0,0,0,0,0};
#pragma unroll
        for (int r = 0; r < 4; r++)
            unpack_acc(img[(size_t)(y0 + r) * 1024 + 55 * 16 + ci4] ^ xm, pk);
        stage_direct(stage + STG_J4 + bi * 512, pk, ci4);
    }
    if (slab == 0) {   // j1: Rtop; j5=(0,0), j6=(0,55)
        u32 pk[8] = {0,0,0,0,0,0,0,0};
#pragma unroll
        for (int jj = 0; jj < 4; jj++) {
            int xx = xo + 16 * jj;
            if (xx < 56) unpack_acc(img[xx * 16 + ci4] ^ xm, pk);
        }
        tree_stage(red, stage + STG_SM + 0 * 8192 + n * 512, pk, t);
        if (t < 32) {
            int which = t >> 4, c4 = t & 15;
            u32 pc[8] = {0,0,0,0,0,0,0,0};
            unpack_acc(img[(which ? 55 : 0) * 16 + c4] ^ xm, pc);
            stage_direct(stage + STG_SM + (2 + which) * 8192 + n * 512, pc, c4);
        }
    }
    if (slab == 13) {  // j2: Rbot; j7=(55,0), j8=(55,55)
        u32 pk[8] = {0,0,0,0,0,0,0,0};
#pragma unroll
        for (int jj = 0; jj < 4; jj++) {
            int xx = xo + 16 * jj;
            if (xx < 56) unpack_acc(img[(size_t)55 * 1024 + xx * 16 + ci4] ^ xm, pk);
        }
        tree_stage(red, stage + STG_SM + 1 * 8192 + n * 512, pk, t);
        if (t < 32) {
            int which = t >> 4, c4 = t & 15;
            u32 pc[8] = {0,0,0,0,0,0,0,0};
            unpack_acc(img[(size_t)55 * 1024 + (which ? 55 : 0) * 16 + c4] ^ xm, pc);
            stage_direct(stage + STG_SM + (4 + which) * 8192 + n * 512, pc, c4);
        }
    }
}

// ---------------- K3b: reduce stage -> st (no atomics) ----------------
__global__ __launch_bounds__(512) void k_red(const int* __restrict__ stage,
                                             int* __restrict__ st) {
    const int offs[9] = {STG_J0, STG_SM, STG_SM + 8192, STG_J3, STG_J4,
                         STG_SM + 2*8192, STG_SM + 3*8192, STG_SM + 4*8192, STG_SM + 5*8192};
    const int cnts[9] = {224, 16, 16, 224, 224, 16, 16, 16, 16};
    int j = blockIdx.x, p = threadIdx.x;
    const int* base = stage + offs[j] + p;
    int cnt = cnts[j];
    int s = 0;
    for (int b = 0; b < cnt; b++) s += base[b * 512];
    st[j * 512 + p] = s;
}

// ---------------- K5/K7: int8 conv 3x3 via MFMA implicit GEMM ----------------
template <int SECOND>
__global__ __launch_bounds__(256, 2) void k_conv(const char* __restrict__ qin,
                                              const char* __restrict__ qw,
                                              const int* __restrict__ wsum,
                                              const char* __restrict__ qid,
                                              const float* __restrict__ g, const float* __restrict__ b,
                                              const float* __restrict__ m_, const float* __restrict__ v,
                                              const float* __restrict__ scal,
                                              float* __restrict__ outp, float* __restrict__ rmax) {
    __shared__ __align__(16) u32 lb[11520];    // B: 576 rows (tap,co) x 20 dw (64B data + 16B pad)
    __shared__ __align__(16) u32 lin[3960];    // input: 3 rows x 66 px x 20 dw
    __shared__ float red[256];
    int n = blockIdx.x, y = blockIdx.y, t = threadIdx.x;
    int w = t >> 6, lane = t & 63, mm = lane & 15, quad = lane >> 4;

    const uint4* bq4 = (const uint4*)qw;                 // 2304 uint4
    for (int j4 = t; j4 < 2304; j4 += 256) {
        int row = j4 >> 2, rem = j4 & 3;
        *(uint4*)&lb[row * 20 + rem * 4] = bq4[j4];
    }
    const uint4* qin4 = (const uint4*)qin;
    for (int g4 = t; g4 < 792; g4 += 256) {              // 3 rows x 264 uint4 (px -1..64)
        int ky = g4 / 264, r = g4 - ky * 264;
        int px = r >> 2, rem = r & 3;
        *(uint4*)&lin[(ky * 66 + px) * 20 + rem * 4] =
            qin4[(size_t)(1 + n * ROWS_PI + y + ky) * 256 - 4 + r];
    }
    __syncthreads();

    v4i acc[4] = {{0,0,0,0},{0,0,0,0},{0,0,0,0},{0,0,0,0}};
#pragma unroll
    for (int ky = 0; ky < 3; ky++) {
#pragma unroll
        for (int kx = 0; kx < 3; kx++) {
            int px = w * 16 + mm + kx;                   // lin idx = (x+kx-1)+1
            v4i a = *(const v4i*)&lin[(ky * 66 + px) * 20 + quad * 4];
            int tap = ky * 3 + kx;
#pragma unroll
            for (int nt = 0; nt < 4; nt++) {
                int co = nt * 16 + mm;
                v4i bf = *(const v4i*)&lb[(tap * 64 + co) * 20 + quad * 4];
                acc[nt] = __builtin_amdgcn_mfma_i32_16x16x64_i8(a, bf, acc[nt], 0, 0, 0);
            }
        }
    }
    // epilogue
    float sIn = SECOND ? scal[3] / 255.f : scal[0] / 127.f;
    float sW  = SECOND ? scal[2] / 127.f : scal[1] / 127.f;
    float sx = scal[0] / 127.f;
    float lmax = 0.f;
    size_t rowb = (size_t)(n * 56 + y) * 3584;
    const signed char* idrow = SECOND ? (const signed char*)(qid + (size_t)(2 + n * ROWS_PI + y) * PADROW)
                                      : (const signed char*)nullptr;
#pragma unroll
    for (int nt = 0; nt < 4; nt++) {
        int co = nt * 16 + mm;
        float inv = g[co] * rsqrtf(v[co] + 1e-5f);
        float alpha = sIn * sW * inv;
        float beta = b[co] - m_[co] * inv;
        int wofs = SECOND ? (wsum[co] << 7) : 0;
#pragma unroll
        for (int r = 0; r < 4; r++) {
            int x = w * 16 + quad * 4 + r;
            if (x < 56) {
                float o = (float)(acc[nt][r] + wofs) * alpha + beta;
                if (SECOND) o += sx * (float)idrow[x * 64 + co];
                outp[rowb + x * 64 + co] = o;
                lmax = fmaxf(lmax, o);
            }
        }
    }
    red[t] = lmax; __syncthreads();
    for (int s = 128; s > 0; s >>= 1) {
        if (t < s) red[t] = fmaxf(red[t], red[t + s]);
        __syncthreads();
    }
    if (t == 0) atomicMax((u32*)rmax, __float_as_uint(red[0]));
}

// ---------------- K6: quantize conv1 output -> q1-128 padded int8 ----------------
__global__ __launch_bounds__(256) void k_quant_relu1(const float* __restrict__ of,
                                                     char* __restrict__ qpad,
                                                     const float* __restrict__ scal) {
    int n = blockIdx.x, yy = blockIdx.y, t = threadIdx.x;
    u32* row = (u32*)(qpad + (size_t)(1 + n * ROWS_PI + yy) * PADROW);
    if (n == 0 && yy == 0) {
        u32* r0 = (u32*)qpad;
        for (int j = t; j < 1024; j += 256) r0[j] = 0x80808080u;
    }
    if (yy == 0 || yy == 57) {
        for (int j = t; j < 1024; j += 256) row[j] = 0x80808080u;
        return;
    }
    int y = yy - 1;
    float s1 = scal[3] / 255.f;
    char* rowb = (char*)row;
    const float* orow = of + (size_t)(n * 56 + y) * 3584;
    for (int idx = t; idx < 3584; idx += 256) {
        float vv = fmaxf(orow[idx], 0.f);
        float q = fminf(rintf(vv / s1), 255.f);
        rowb[idx] = (char)((int)q - 128);
    }
    for (int j = 896 + t; j < 1024; j += 256) row[j] = 0x80808080u;
}

// ---------------- K8: final quantize + NHWC->NCHW transpose ----------------
__global__ __launch_bounds__(256) void k_final(const float* __restrict__ of,
                                               const float* __restrict__ scal,
                                               float* __restrict__ outp) {
    int n = blockIdx.x, y = blockIdx.y, t = threadIdx.x;
    __shared__ float lt[64 * 57];
    float s2 = scal[4] / 255.f;
    const float* orow = of + (size_t)(n * 56 + y) * 3584;
    for (int idx = t; idx < 3584; idx += 256) {
        int co = idx & 63, xx = idx >> 6;
        float vv = fmaxf(orow[idx], 0.f);
        float q = fminf(rintf(vv / s2), 255.f);
        lt[co * 57 + xx] = q * s2;
    }
    __syncthreads();
    for (int idx = t; idx < 3584; idx += 256) {
        int co = idx / 56, xx = idx - co * 56;
        outp[(size_t)n * 200704 + (size_t)co * 3136 + y * 56 + xx] = lt[co * 57 + xx];
    }
}

// ---------------- K9: combine bit-stats into HM_act / HM_energy ----------------
__global__ __launch_bounds__(512) void k_hm(const int* __restrict__ stx, const int* __restrict__ stq,
                                            const int* __restrict__ wb1, const int* __restrict__ wb2,
                                            float* __restrict__ outp) {
    int t = threadIdx.x;   // t = ci*8 + k
    long long act = 0, en = 0;
#pragma unroll
    for (int w = 0; w < 2; w++) {
        const int* st = w ? stq : stx;
        const int* wb = w ? wb2 : wb1;
        long long s[9];
#pragma unroll
        for (int j = 0; j < 9; j++) s[j] = st[j * 512 + t];
        const int* wrow = wb + t * 9;
        int w0 = wrow[0], w1_ = wrow[1], w2_ = wrow[2], w3 = wrow[3], w4 = wrow[4],
            w5 = wrow[5], w6 = wrow[6], w7 = wrow[7], w8 = wrow[8];
        long long wall = (long long)w0 + w1_ + w2_ + w3 + w4 + w5 + w6 + w7 + w8;
        long long wr0 = (long long)w0 + w1_ + w2_;
        long long wr2 = (long long)w6 + w7 + w8;
        long long wc0 = (long long)w0 + w3 + w6;
        long long wc2 = (long long)w2_ + w5 + w8;
        en += s[0] * wall - s[1] * wr2 - s[2] * wr0 - s[3] * wc2 - s[4] * wc0
            + s[5] * w8 + s[6] * w6 + s[7] * w2_ + s[8] * w0;
        act += s[0];
    }
    __shared__ long long r1[512];
    r1[t] = en; __syncthreads();
    for (int s = 256; s > 0; s >>= 1) { if (t < s) r1[t] += r1[t + s]; __syncthreads(); }
    long long etot = r1[0]; __syncthreads();
    r1[t] = act; __syncthreads();
    for (int s = 256; s > 0; s >>= 1) { if (t < s) r1[t] += r1[t + s]; __syncthreads(); }
    if (t == 0) {
        outp[OUTN]     = (float)r1[0];   // HM_act
        outp[OUTN + 1] = (float)etot;    // HM_energy
    }
}

extern "C" void kernel_launch(void* const* d_in, const int* in_sizes, int n_in,
                              void* d_out, int out_size, void* d_ws, size_t ws_size,
                              hipStream_t stream) {
    if (ws_size < WS_NEED) return;
    const float* x  = (const float*)d_in[0];
    const float* w1 = (const float*)d_in[1];
    const float* w2 = (const float*)d_in[2];
    const float* g1 = (const float*)d_in[3];
    const float* b1 = (const float*)d_in[4];
    const float* m1 = (const float*)d_in[5];
    const float* v1 = (const float*)d_in[6];
    const float* g2 = (const float*)d_in[7];
    const float* b2 = (const float*)d_in[8];
    const float* m2 = (const float*)d_in[9];
    const float* v2 = (const float*)d_in[10];
    char* ws = (char*)d_ws;
    float* scal = (float*)ws;
    char* qx = ws + OFS_QX;
    char* q1 = ws + OFS_Q1;
    float* o1 = (float*)(ws + OFS_O1);
    float* o2 = (float*)(ws + OFS_O2);
    int* stage = (int*)(ws + OFS_O2);   // overlay: dead while stats/red run
    char* qw1 = ws + OFS_QW1;
    char* qw2 = ws + OFS_QW2;
    int* wb1 = (int*)(ws + OFS_WB1);
    int* wb2 = (int*)(ws + OFS_WB2);
    int* wsum = (int*)(ws + OFS_WSUM);
    int* stx = (int*)(ws + OFS_STX);
    int* stq = (int*)(ws + OFS_STQ);
    float* outp = (float*)d_out;

    k_init<<<1, 256, 0, stream>>>(scal, wsum);
    k_absmax<<<dim3(1024, 3), 256, 0, stream>>>(x, w1, w2, scal);
    k_quant_x<<<dim3(16, 58), 256, 0, stream>>>(x, qx, scal);
    k_quant_w<<<dim3(2, 9), 256, 0, stream>>>(w1, w2, qw1, qw2, wb1, wb2, wsum, scal);
    k_stats<<<dim3(16, 14), 256, 0, stream>>>(qx, 0u, stage);
    k_red<<<9, 512, 0, stream>>>(stage, stx);
    k_conv<0><<<dim3(16, 56), 256, 0, stream>>>(qx, qw1, nullptr, nullptr,
                                                g1, b1, m1, v1, scal, o1, scal + 3);
    k_quant_relu1<<<dim3(16, 58), 256, 0, stream>>>(o1, q1, scal);
    k_stats<<<dim3(16, 14), 256, 0, stream>>>(q1, 0x80u, stage);
    k_red<<<9, 512, 0, stream>>>(stage, stq);
    k_conv<1><<<dim3(16, 56), 256, 0, stream>>>(q1, qw2, wsum, qx,
                                                g2, b2, m2, v2, scal, o2, scal + 4);
    k_final<<<dim3(16, 56), 256, 0, stream>>>(o2, scal, outp);
    k_hm<<<1, 512, 0, stream>>>(stx, stq, wb1, wb2, outp);
}

// Round 7
// 241.032 us; speedup vs baseline: 1.3586x; 1.1465x over previous
//
#include <hip/hip_runtime.h>

using u32 = unsigned int;
typedef int v4i __attribute__((ext_vector_type(4)));

// ---------------- workspace layout (bytes) ----------------
constexpr int  N_IMG   = 16;
constexpr int  PADROW  = 4096;          // 64 cols * 64 ch bytes
constexpr int  ROWS_PI = 58;            // 56 real + top/bottom pad rows
constexpr size_t OFS_QX  = 4096;
constexpr size_t SZ_QPAD = (size_t)(1 + N_IMG * ROWS_PI) * PADROW;   // 3,805,184
constexpr size_t OFS_Q1  = OFS_QX + SZ_QPAD;
constexpr size_t OFS_O1  = OFS_Q1 + SZ_QPAD;
constexpr size_t SZ_OF   = (size_t)N_IMG * 56 * 56 * 64 * 4;         // 12,845,056
constexpr size_t OFS_O2  = OFS_O1 + SZ_OF;                           // also: stage overlay
constexpr size_t OFS_QW1 = OFS_O2 + SZ_OF;
constexpr size_t OFS_QW2 = OFS_QW1 + 36864;
constexpr size_t OFS_WB1 = OFS_QW2 + 36864;
constexpr size_t OFS_WB2 = OFS_WB1 + 18432;
constexpr size_t OFS_WSUM= OFS_WB2 + 18432;
constexpr size_t OFS_STX = OFS_WSUM + 256;      // 4608 ints
constexpr size_t OFS_STQ = OFS_STX + 18432;
constexpr size_t WS_NEED = OFS_STQ + 18432;
constexpr size_t OUTN    = (size_t)16 * 64 * 56 * 56;                // 3,211,264

// stage layout (ints), overlaid on o2 region (dead until conv2; k_red runs before conv2):
constexpr int STG_J0 = 0;
constexpr int STG_J3 = 224 * 512;
constexpr int STG_J4 = 2 * 224 * 512;
constexpr int STG_SM = 3 * 224 * 512;   // + idx*8192: j1=0,j2=1,(0,0)=2,(0,55)=3,(55,0)=4,(55,55)=5
constexpr int STG_TOTAL = 3 * 224 * 512 + 6 * 16 * 512;   // 393,216 ints = 1.57 MB

// ---------------- K0: zero scalars + wsum ----------------
__global__ __launch_bounds__(256) void k_init(float* scal, int* wsum) {
    int i = threadIdx.x;
    if (i < 8) scal[i] = 0.f;
    if (i < 64) wsum[i] = 0;
}

// ---------------- K1: absmax of x / w1 / w2 ----------------
__global__ __launch_bounds__(256) void k_absmax(const float* __restrict__ x,
                                                const float* __restrict__ w1,
                                                const float* __restrict__ w2,
                                                float* __restrict__ scal) {
    const float* p; int n; int slot;
    if (blockIdx.y == 0)      { p = x;  n = 16*64*56*56; slot = 0; }
    else if (blockIdx.y == 1) { p = w1; n = 64*64*9;     slot = 1; }
    else                      { p = w2; n = 64*64*9;     slot = 2; }
    float m = 0.f;
    for (int i = blockIdx.x * 256 + threadIdx.x; i < n; i += gridDim.x * 256)
        m = fmaxf(m, fabsf(p[i]));
    __shared__ float red[256];
    red[threadIdx.x] = m; __syncthreads();
    for (int s = 128; s > 0; s >>= 1) {
        if (threadIdx.x < s) red[threadIdx.x] = fmaxf(red[threadIdx.x], red[threadIdx.x + s]);
        __syncthreads();
    }
    if (threadIdx.x == 0) atomicMax((u32*)(scal + slot), __float_as_uint(red[0]));
}

// ---------------- stats helpers ----------------
static __device__ __forceinline__ void unpack_acc(u32 v, u32 pk[8]) {
#pragma unroll
    for (int k = 0; k < 8; k++) pk[k] += (v >> k) & 0x01010101u;
}

// packed-byte tree reduce over xo = t>>4 (16 groups) for each (c4 = t&15, k); plain stores.
static __device__ __forceinline__ void tree_stage(u32* red, int* dst, const u32 pk[8], int t) {
#pragma unroll
    for (int k = 0; k < 8; k++) red[k * 256 + t] = pk[k];
    __syncthreads();
    if (t < 128) {
#pragma unroll
        for (int k = 0; k < 8; k++) red[k * 256 + t] += red[k * 256 + t + 128];
    }
    __syncthreads();
    if (t < 64) {
#pragma unroll
        for (int k = 0; k < 8; k++) red[k * 256 + t] += red[k * 256 + t + 64];
    }
    __syncthreads();
    if (t < 32) {
#pragma unroll
        for (int k = 0; k < 8; k++) red[k * 256 + t] += red[k * 256 + t + 32];
    }
    __syncthreads();
#pragma unroll
    for (int p = t; p < 512; p += 256) {
        int ci = p >> 3, k = p & 7, ci4 = ci >> 2, b = ci & 3;
        u32 e = red[k * 256 + ci4], o = red[k * 256 + 16 + ci4];
        dst[p] = (int)((e >> (8 * b)) & 0xFF) + (int)((o >> (8 * b)) & 0xFF);
    }
    __syncthreads();
}

// 16 single-writer threads (c4 = 0..15) each store 32 of the 512 entries
static __device__ __forceinline__ void stage_direct(int* dst, const u32 pk[8], int c4) {
#pragma unroll
    for (int k = 0; k < 8; k++)
#pragma unroll
        for (int b = 0; b < 4; b++)
            dst[(c4 * 4 + b) * 8 + k] = (int)((pk[k] >> (8 * b)) & 0xFF);
}

// ---------------- K2: fused quantize x (NCHW->padded NHWC int8) + bit-stats ----------------
// grid (16,14); thread t: c4 = t&15 (4-channel group), xg = t>>4 (4-pixel group, 0..13 active).
__global__ __launch_bounds__(256) void k_qxs(const float* __restrict__ x,
                                             char* __restrict__ qpad,
                                             const float* __restrict__ scal,
                                             int* __restrict__ stg) {
    int n = blockIdx.x, slab = blockIdx.y, t = threadIdx.x;
    int c4 = t & 15, xg = t >> 4;
    __shared__ u32 lq[3584];     // 4 rows x 896 dwords
    __shared__ u32 red[2048];
    float sx = scal[0] / 127.f;
    int y0 = slab * 4, bi = n * 14 + slab;
    bool doT = (slab == 0), doB = (slab == 13);
    bool colL = (xg == 0), colR = (xg == 13);
    u32 pk[8]  = {0,0,0,0,0,0,0,0};
    u32 pkE[8] = {0,0,0,0,0,0,0,0};
    u32 pkS[8] = {0,0,0,0,0,0,0,0};   // side col (L or R)
    u32 pkC[8] = {0,0,0,0,0,0,0,0};   // corner

    if (xg < 14) {
        int c0 = c4 * 4, xx0 = xg * 4;
        const float* base = x + (size_t)n * 200704 + (size_t)c0 * 3136 + (size_t)y0 * 56 + xx0;
#pragma unroll
        for (int r = 0; r < 4; r++) {
            bool er = (doT && r == 0) || (doB && r == 3);
            float4 f[4];
#pragma unroll
            for (int cc = 0; cc < 4; cc++)
                f[cc] = *(const float4*)(base + (size_t)cc * 3136 + r * 56);
            int qv[4][4];
#pragma unroll
            for (int cc = 0; cc < 4; cc++) {
                float vv[4] = {f[cc].x, f[cc].y, f[cc].z, f[cc].w};
#pragma unroll
                for (int i = 0; i < 4; i++) {
                    float q = rintf(vv[i] / sx);
                    q = fminf(fmaxf(q, -127.f), 127.f);
                    qv[cc][i] = (int)q;
                }
            }
#pragma unroll
            for (int i = 0; i < 4; i++) {
                u32 d = ((u32)(unsigned char)(signed char)qv[0][i])
                      | ((u32)(unsigned char)(signed char)qv[1][i] << 8)
                      | ((u32)(unsigned char)(signed char)qv[2][i] << 16)
                      | ((u32)(unsigned char)(signed char)qv[3][i] << 24);
                lq[r * 896 + (xx0 + i) * 16 + c4] = d;
                unpack_acc(d, pk);
                if (er) unpack_acc(d, pkE);
                if ((colL && i == 0) || (colR && i == 3)) {
                    unpack_acc(d, pkS);
                    if (er) unpack_acc(d, pkC);
                }
            }
        }
    }
    __syncthreads();
    // global padded rows
    for (int idx = t; idx < 4096; idx += 256) {
        int r = idx >> 10, jd = idx & 1023;
        u32 val = (jd < 896) ? lq[r * 896 + jd] : 0u;
        ((u32*)qpad)[(size_t)(2 + n * ROWS_PI + y0 + r) * 1024 + jd] = val;
    }
    if (doT) {
        u32* row = (u32*)(qpad + (size_t)(1 + n * ROWS_PI) * PADROW);
        for (int j = t; j < 1024; j += 256) row[j] = 0u;
        if (n == 0) {
            u32* r0 = (u32*)qpad;
            for (int j = t; j < 1024; j += 256) r0[j] = 0u;
        }
    }
    if (doB) {
        u32* row = (u32*)(qpad + (size_t)(1 + n * ROWS_PI + 57) * PADROW);
        for (int j = t; j < 1024; j += 256) row[j] = 0u;
    }
    // staging
    tree_stage(red, stg + STG_J0 + bi * 512, pk, t);
    if (doT) tree_stage(red, stg + STG_SM + 0 * 8192 + n * 512, pkE, t);
    if (doB) tree_stage(red, stg + STG_SM + 1 * 8192 + n * 512, pkE, t);
    if (colL) {
        stage_direct(stg + STG_J3 + bi * 512, pkS, c4);
        if (doT) stage_direct(stg + STG_SM + 2 * 8192 + n * 512, pkC, c4);
        if (doB) stage_direct(stg + STG_SM + 4 * 8192 + n * 512, pkC, c4);
    }
    if (colR) {
        stage_direct(stg + STG_J4 + bi * 512, pkS, c4);
        if (doT) stage_direct(stg + STG_SM + 3 * 8192 + n * 512, pkC, c4);
        if (doB) stage_direct(stg + STG_SM + 5 * 8192 + n * 512, pkC, c4);
    }
}

// ---------------- K2b: quantize weights -> [tap][co][ci], WB bit-stats, wsum ----------------
__global__ __launch_bounds__(256) void k_quant_w(const float* __restrict__ w1,
                                                 const float* __restrict__ w2,
                                                 char* __restrict__ qw1, char* __restrict__ qw2,
                                                 int* __restrict__ wb1, int* __restrict__ wb2,
                                                 int* __restrict__ wsum,
                                                 const float* __restrict__ scal) {
    int wsel = blockIdx.x, kp = blockIdx.y;
    const float* w = wsel ? w2 : w1;
    char* qw = wsel ? qw2 : qw1;
    int* wb  = wsel ? wb2 : wb1;
    float s = scal[1 + wsel] / 127.f;
    int t = threadIdx.x, co = t & 63, cg = t >> 6;
    int ci0 = cg * 16;
    signed char qv[16];
    int qsum = 0;
#pragma unroll
    for (int i = 0; i < 16; i++) {
        int ci = ci0 + i;
        float v = w[((size_t)co * 64 + ci) * 9 + kp];
        float qf = rintf(v / s);
        qf = fminf(fmaxf(qf, -127.f), 127.f);
        int q = (int)qf;
        qv[i] = (signed char)q;
        qsum += q;
    }
    u32 pk[4];
#pragma unroll
    for (int d = 0; d < 4; d++)
        pk[d] = ((u32)(unsigned char)qv[d*4]) | ((u32)(unsigned char)qv[d*4+1] << 8)
              | ((u32)(unsigned char)qv[d*4+2] << 16) | ((u32)(unsigned char)qv[d*4+3] << 24);
    *(uint4*)&qw[(size_t)(kp * 64 + co) * 64 + ci0] = *(uint4*)pk;
#pragma unroll
    for (int i = 0; i < 16; i++) {
        u32 u = (u32)(unsigned char)qv[i];
#pragma unroll
        for (int k = 0; k < 8; k++) {
            unsigned long long bal = __ballot((u >> k) & 1);
            if (co == 0) wb[((ci0 + i) * 8 + k) * 9 + kp] = __popcll(bal);
        }
    }
    if (wsel == 1) {
        __shared__ int wsl[256];
        wsl[t] = qsum; __syncthreads();
        if (t < 64) {
            int sum = wsl[t] + wsl[t + 64] + wsl[t + 128] + wsl[t + 192];
            atomicAdd(&wsum[t], sum);
        }
    }
}

// ---------------- K6: fused quant_relu1 (o1 -> q1-128 padded) + bit-stats ----------------
// grid (16,14); thread t processes dwords j = t + 256m, m<14 of the 4x896 dword slab.
__global__ __launch_bounds__(256) void k_qr1s(const float* __restrict__ of,
                                              char* __restrict__ qpad,
                                              const float* __restrict__ scal,
                                              int* __restrict__ stg) {
    int n = blockIdx.x, slab = blockIdx.y, t = threadIdx.x;
    __shared__ u32 red[2048];
    float s1 = scal[3] / 255.f;
    int y0 = slab * 4, bi = n * 14 + slab;
    bool doT = (slab == 0), doB = (slab == 13);
    u32 pk[8]  = {0,0,0,0,0,0,0,0};
    u32 pkE[8] = {0,0,0,0,0,0,0,0};
    u32 pkL[8] = {0,0,0,0,0,0,0,0};
    u32 pkR[8] = {0,0,0,0,0,0,0,0};
    u32 pkC[8] = {0,0,0,0,0,0,0,0};
    const float4* o4 = (const float4*)(of + (size_t)(n * 56 + y0) * 3584);
    u32* qd = (u32*)qpad;
#pragma unroll
    for (int m = 0; m < 14; m++) {
        int j = t + 256 * m;
        int r = j / 896;
        int rem = j - r * 896;
        int xxp = rem >> 4;
        float4 f = o4[j];
        float vv[4] = {f.x, f.y, f.z, f.w};
        u32 d = 0;
#pragma unroll
        for (int i = 0; i < 4; i++) {
            float q = fminf(rintf(fmaxf(vv[i], 0.f) / s1), 255.f);
            d |= ((u32)((int)q - 128) & 0xFFu) << (8 * i);
        }
        qd[(size_t)(2 + n * ROWS_PI + y0 + r) * 1024 + rem] = d;
        u32 dx = d ^ 0x80808080u;
        unpack_acc(dx, pk);
        bool er = (doT && r == 0) || (doB && r == 3);
        if (er) unpack_acc(dx, pkE);
        if (xxp == 0) {
            unpack_acc(dx, pkL);
            if (er) unpack_acc(dx, pkC);
        } else if (xxp == 55) {
            unpack_acc(dx, pkR);
            if (er) unpack_acc(dx, pkC);
        }
    }
    // per-row pad dwords 896..1023
    for (int idx = t; idx < 512; idx += 256) {
        int r = idx >> 7, jd = 896 + (idx & 127);
        qd[(size_t)(2 + n * ROWS_PI + y0 + r) * 1024 + jd] = 0x80808080u;
    }
    if (doT) {
        u32* row = (u32*)(qpad + (size_t)(1 + n * ROWS_PI) * PADROW);
        for (int j = t; j < 1024; j += 256) row[j] = 0x80808080u;
        if (n == 0) {
            u32* r0 = (u32*)qpad;
            for (int j = t; j < 1024; j += 256) r0[j] = 0x80808080u;
        }
    }
    if (doB) {
        u32* row = (u32*)(qpad + (size_t)(1 + n * ROWS_PI + 57) * PADROW);
        for (int j = t; j < 1024; j += 256) row[j] = 0x80808080u;
    }
    // staging (trees: contributions may come from multiple t>>4 groups)
    tree_stage(red, stg + STG_J0 + bi * 512, pk, t);
    tree_stage(red, stg + STG_J3 + bi * 512, pkL, t);
    tree_stage(red, stg + STG_J4 + bi * 512, pkR, t);
    if (doT) tree_stage(red, stg + STG_SM + 0 * 8192 + n * 512, pkE, t);
    if (doB) tree_stage(red, stg + STG_SM + 1 * 8192 + n * 512, pkE, t);
    // corners: single-writer threads (verified per-m mapping)
    if (doT) {
        if (t < 16) stage_direct(stg + STG_SM + 2 * 8192 + n * 512, pkC, t);
        else if (t >= 112 && t < 128) stage_direct(stg + STG_SM + 3 * 8192 + n * 512, pkC, t - 112);
    }
    if (doB) {
        if (t >= 128 && t < 144) stage_direct(stg + STG_SM + 4 * 8192 + n * 512, pkC, t - 128);
        else if (t >= 240) stage_direct(stg + STG_SM + 5 * 8192 + n * 512, pkC, t - 240);
    }
}

// ---------------- K3b: reduce both stages -> stx/stq (no atomics) ----------------
__global__ __launch_bounds__(512) void k_red(const int* __restrict__ stgX,
                                             const int* __restrict__ stgQ,
                                             int* __restrict__ stx, int* __restrict__ stq) {
    const int offs[9] = {STG_J0, STG_SM, STG_SM + 8192, STG_J3, STG_J4,
                         STG_SM + 2*8192, STG_SM + 3*8192, STG_SM + 4*8192, STG_SM + 5*8192};
    const int cnts[9] = {224, 16, 16, 224, 224, 16, 16, 16, 16};
    int j = blockIdx.x, p = threadIdx.x;
    const int* stage = blockIdx.y ? stgQ : stgX;
    int* st = blockIdx.y ? stq : stx;
    const int* base = stage + offs[j] + p;
    int cnt = cnts[j];
    int s = 0;
    for (int b = 0; b < cnt; b++) s += base[b * 512];
    st[j * 512 + p] = s;
}

// ---------------- K5/K7: int8 conv 3x3 via MFMA implicit GEMM ----------------
template <int SECOND>
__global__ __launch_bounds__(256, 2) void k_conv(const char* __restrict__ qin,
                                              const char* __restrict__ qw,
                                              const int* __restrict__ wsum,
                                              const char* __restrict__ qid,
                                              const float* __restrict__ g, const float* __restrict__ b,
                                              const float* __restrict__ m_, const float* __restrict__ v,
                                              const float* __restrict__ scal,
                                              float* __restrict__ outp, float* __restrict__ rmax) {
    __shared__ __align__(16) u32 lb[11520];    // B: 576 rows (tap,co) x 20 dw (64B data + 16B pad)
    __shared__ __align__(16) u32 lin[3960];    // input: 3 rows x 66 px x 20 dw
    __shared__ float red[256];
    int n = blockIdx.x, y = blockIdx.y, t = threadIdx.x;
    int w = t >> 6, lane = t & 63, mm = lane & 15, quad = lane >> 4;

    const uint4* bq4 = (const uint4*)qw;                 // 2304 uint4
    for (int j4 = t; j4 < 2304; j4 += 256) {
        int row = j4 >> 2, rem = j4 & 3;
        *(uint4*)&lb[row * 20 + rem * 4] = bq4[j4];
    }
    const uint4* qin4 = (const uint4*)qin;
    for (int g4 = t; g4 < 792; g4 += 256) {              // 3 rows x 264 uint4 (px -1..64)
        int ky = g4 / 264, r = g4 - ky * 264;
        int px = r >> 2, rem = r & 3;
        *(uint4*)&lin[(ky * 66 + px) * 20 + rem * 4] =
            qin4[(size_t)(1 + n * ROWS_PI + y + ky) * 256 - 4 + r];
    }
    __syncthreads();

    v4i acc[4] = {{0,0,0,0},{0,0,0,0},{0,0,0,0},{0,0,0,0}};
#pragma unroll
    for (int ky = 0; ky < 3; ky++) {
#pragma unroll
        for (int kx = 0; kx < 3; kx++) {
            int px = w * 16 + mm + kx;                   // lin idx = (x+kx-1)+1
            v4i a = *(const v4i*)&lin[(ky * 66 + px) * 20 + quad * 4];
            int tap = ky * 3 + kx;
#pragma unroll
            for (int nt = 0; nt < 4; nt++) {
                int co = nt * 16 + mm;
                v4i bf = *(const v4i*)&lb[(tap * 64 + co) * 20 + quad * 4];
                acc[nt] = __builtin_amdgcn_mfma_i32_16x16x64_i8(a, bf, acc[nt], 0, 0, 0);
            }
        }
    }
    // epilogue
    float sIn = SECOND ? scal[3] / 255.f : scal[0] / 127.f;
    float sW  = SECOND ? scal[2] / 127.f : scal[1] / 127.f;
    float sx = scal[0] / 127.f;
    float lmax = 0.f;
    size_t rowb = (size_t)(n * 56 + y) * 3584;
    const signed char* idrow = SECOND ? (const signed char*)(qid + (size_t)(2 + n * ROWS_PI + y) * PADROW)
                                      : (const signed char*)nullptr;
#pragma unroll
    for (int nt = 0; nt < 4; nt++) {
        int co = nt * 16 + mm;
        float inv = g[co] * rsqrtf(v[co] + 1e-5f);
        float alpha = sIn * sW * inv;
        float beta = b[co] - m_[co] * inv;
        int wofs = SECOND ? (wsum[co] << 7) : 0;
#pragma unroll
        for (int r = 0; r < 4; r++) {
            int x = w * 16 + quad * 4 + r;
            if (x < 56) {
                float o = (float)(acc[nt][r] + wofs) * alpha + beta;
                if (SECOND) o += sx * (float)idrow[x * 64 + co];
                outp[rowb + x * 64 + co] = o;
                lmax = fmaxf(lmax, o);
            }
        }
    }
    red[t] = lmax; __syncthreads();
    for (int s = 128; s > 0; s >>= 1) {
        if (t < s) red[t] = fmaxf(red[t], red[t + s]);
        __syncthreads();
    }
    if (t == 0) atomicMax((u32*)rmax, __float_as_uint(red[0]));
}

// ---------------- K8: final quantize + NHWC->NCHW transpose ----------------
__global__ __launch_bounds__(256) void k_final(const float* __restrict__ of,
                                               const float* __restrict__ scal,
                                               float* __restrict__ outp) {
    int n = blockIdx.x, y = blockIdx.y, t = threadIdx.x;
    __shared__ float lt[64 * 57];
    float s2 = scal[4] / 255.f;
    const float* orow = of + (size_t)(n * 56 + y) * 3584;
    for (int idx = t; idx < 3584; idx += 256) {
        int co = idx & 63, xx = idx >> 6;
        float vv = fmaxf(orow[idx], 0.f);
        float q = fminf(rintf(vv / s2), 255.f);
        lt[co * 57 + xx] = q * s2;
    }
    __syncthreads();
    for (int idx = t; idx < 3584; idx += 256) {
        int co = idx / 56, xx = idx - co * 56;
        outp[(size_t)n * 200704 + (size_t)co * 3136 + y * 56 + xx] = lt[co * 57 + xx];
    }
}

// ---------------- K9: combine bit-stats into HM_act / HM_energy ----------------
__global__ __launch_bounds__(512) void k_hm(const int* __restrict__ stx, const int* __restrict__ stq,
                                            const int* __restrict__ wb1, const int* __restrict__ wb2,
                                            float* __restrict__ outp) {
    int t = threadIdx.x;   // t = ci*8 + k
    long long act = 0, en = 0;
#pragma unroll
    for (int w = 0; w < 2; w++) {
        const int* st = w ? stq : stx;
        const int* wb = w ? wb2 : wb1;
        long long s[9];
#pragma unroll
        for (int j = 0; j < 9; j++) s[j] = st[j * 512 + t];
        const int* wrow = wb + t * 9;
        int w0 = wrow[0], w1_ = wrow[1], w2_ = wrow[2], w3 = wrow[3], w4 = wrow[4],
            w5 = wrow[5], w6 = wrow[6], w7 = wrow[7], w8 = wrow[8];
        long long wall = (long long)w0 + w1_ + w2_ + w3 + w4 + w5 + w6 + w7 + w8;
        long long wr0 = (long long)w0 + w1_ + w2_;
        long long wr2 = (long long)w6 + w7 + w8;
        long long wc0 = (long long)w0 + w3 + w6;
        long long wc2 = (long long)w2_ + w5 + w8;
        en += s[0] * wall - s[1] * wr2 - s[2] * wr0 - s[3] * wc2 - s[4] * wc0
            + s[5] * w8 + s[6] * w6 + s[7] * w2_ + s[8] * w0;
        act += s[0];
    }
    __shared__ long long r1[512];
    r1[t] = en; __syncthreads();
    for (int s = 256; s > 0; s >>= 1) { if (t < s) r1[t] += r1[t + s]; __syncthreads(); }
    long long etot = r1[0]; __syncthreads();
    r1[t] = act; __syncthreads();
    for (int s = 256; s > 0; s >>= 1) { if (t < s) r1[t] += r1[t + s]; __syncthreads(); }
    if (t == 0) {
        outp[OUTN]     = (float)r1[0];   // HM_act
        outp[OUTN + 1] = (float)etot;    // HM_energy
    }
}

extern "C" void kernel_launch(void* const* d_in, const int* in_sizes, int n_in,
                              void* d_out, int out_size, void* d_ws, size_t ws_size,
                              hipStream_t stream) {
    if (ws_size < WS_NEED) return;
    const float* x  = (const float*)d_in[0];
    const float* w1 = (const float*)d_in[1];
    const float* w2 = (const float*)d_in[2];
    const float* g1 = (const float*)d_in[3];
    const float* b1 = (const float*)d_in[4];
    const float* m1 = (const float*)d_in[5];
    const float* v1 = (const float*)d_in[6];
    const float* g2 = (const float*)d_in[7];
    const float* b2 = (const float*)d_in[8];
    const float* m2 = (const float*)d_in[9];
    const float* v2 = (const float*)d_in[10];
    char* ws = (char*)d_ws;
    float* scal = (float*)ws;
    char* qx = ws + OFS_QX;
    char* q1 = ws + OFS_Q1;
    float* o1 = (float*)(ws + OFS_O1);
    float* o2 = (float*)(ws + OFS_O2);
    int* stgX = (int*)(ws + OFS_O2);          // overlay: dead until conv2 (k_red runs first)
    int* stgQ = stgX + STG_TOTAL;
    char* qw1 = ws + OFS_QW1;
    char* qw2 = ws + OFS_QW2;
    int* wb1 = (int*)(ws + OFS_WB1);
    int* wb2 = (int*)(ws + OFS_WB2);
    int* wsum = (int*)(ws + OFS_WSUM);
    int* stx = (int*)(ws + OFS_STX);
    int* stq = (int*)(ws + OFS_STQ);
    float* outp = (float*)d_out;

    k_init<<<1, 256, 0, stream>>>(scal, wsum);
    k_absmax<<<dim3(1024, 3), 256, 0, stream>>>(x, w1, w2, scal);
    k_qxs<<<dim3(16, 14), 256, 0, stream>>>(x, qx, scal, stgX);
    k_quant_w<<<dim3(2, 9), 256, 0, stream>>>(w1, w2, qw1, qw2, wb1, wb2, wsum, scal);
    k_conv<0><<<dim3(16, 56), 256, 0, stream>>>(qx, qw1, nullptr, nullptr,
                                                g1, b1, m1, v1, scal, o1, scal + 3);
    k_qr1s<<<dim3(16, 14), 256, 0, stream>>>(o1, q1, scal, stgQ);
    k_red<<<dim3(9, 2), 512, 0, stream>>>(stgX, stgQ, stx, stq);
    k_conv<1><<<dim3(16, 56), 256, 0, stream>>>(q1, qw2, wsum, qx,
                                                g2, b2, m2, v2, scal, o2, scal + 4);
    k_final<<<dim3(16, 56), 256, 0, stream>>>(o2, scal, outp);
    k_hm<<<1, 512, 0, stream>>>(stx, stq, wb1, wb2, outp);
}